// Round 5
// baseline (374.735 us; speedup 1.0000x reference)
//
#include <hip/hip_runtime.h>
#include <math.h>

namespace {

constexpr int kB = 32;
constexpr int kS = 4096;
constexpr int kD = 2048;
constexpr int kNW = 4;   // waves per block

// Pass 1: single-read flash partial.
// grid = (nchunk, B), block = 256 = 4 waves; __launch_bounds__(256,4) caps
// VGPR at 128 so 4 waves/SIMD (16 waves/CU) are resident -> decorrelated
// vmcnt stalls keep the HBM pipe full. decoder_hidden lives in LDS (shared by
// all 4 waves) instead of 32 VGPRs; an opaque-index asm per row prevents the
// compiler from LICM'ing it back into registers. Each wave owns rows
// {w, w+4, ...}; a row lives in 32 VGPRs (lane covers d = 256*k + 4*lane),
// 2-deep rotated pipeline. At the end the 4 wave-partials are tree-merged in
// LDS so each block writes ONE partial (8.4 MB total instead of 33.6 MB).
__global__ __launch_bounds__(256, 4)
void attn_partial(const float* __restrict__ h,      // [B, D]
                  const float* __restrict__ E,      // [B, S, D]
                  float* __restrict__ acc_ws,       // [B, nchunk, D]
                  float* __restrict__ ml_ws,        // [B, nchunk, 2]
                  int nchunk)
{
    const int c    = blockIdx.x;
    const int b    = blockIdx.y;
    const int t    = threadIdx.x;
    const int lane = t & 63;
    const int wave = t >> 6;
    const int cs   = kS / nchunk;     // rows per chunk
    const int s0   = c * cs;
    const int n    = cs / kNW;        // rows per wave (even)

    __shared__ float4 sh_h[512];          // 8 KB: decoder_hidden row
    __shared__ float4 sh_merge[2][512];   // 16 KB: wave-partial exchange
    __shared__ float  sh_ml[2][2];

    // stage h into LDS (8 KB), cooperatively
    const float* hb = h + (size_t)b * kD;
    for (int i = t; i < 512; i += 256)
        sh_h[i] = *reinterpret_cast<const float4*>(hb + 4 * i);
    __syncthreads();

    float4 acc[8];
#pragma unroll
    for (int k = 0; k < 8; ++k) acc[k] = make_float4(0.f, 0.f, 0.f, 0.f);
    float m = -INFINITY, l = 0.f;

    const float* Eb = E + ((size_t)b * kS + s0 + wave) * kD + 4 * lane;

    float4 e0[8], e1[8];

#define LOAD(buf, i)                                                         \
    {                                                                        \
        const float* _row = Eb + (size_t)(i) * (kNW * kD);                   \
        _Pragma("unroll")                                                    \
        for (int k = 0; k < 8; ++k)                                          \
            buf[k] = *reinterpret_cast<const float4*>(_row + 256 * k);       \
    }

#define COMPUTE(buf)                                                         \
    {                                                                        \
        int hidx = lane;                                                     \
        asm volatile("" : "+v"(hidx));   /* opaque: defeat LICM of sh_h */   \
        float p = 0.f;                                                       \
        _Pragma("unroll")                                                    \
        for (int k = 0; k < 8; ++k) {                                        \
            const float4 hk = sh_h[k * 64 + hidx];                           \
            p += buf[k].x * hk.x + buf[k].y * hk.y +                         \
                 buf[k].z * hk.z + buf[k].w * hk.w;                          \
        }                                                                    \
        _Pragma("unroll")                                                    \
        for (int off = 32; off > 0; off >>= 1)                               \
            p += __shfl_xor(p, off, 64);                                     \
        float w;                                                             \
        if (p > m) {                 /* wave-uniform; rare */                \
            const float scale = __expf(m - p);                               \
            _Pragma("unroll")                                                \
            for (int k = 0; k < 8; ++k) {                                    \
                acc[k].x *= scale; acc[k].y *= scale;                        \
                acc[k].z *= scale; acc[k].w *= scale;                        \
            }                                                                \
            l *= scale;                                                      \
            m = p;                                                           \
            w = 1.f;                                                         \
        } else {                                                             \
            w = __expf(p - m);                                               \
        }                                                                    \
        l += w;                                                              \
        _Pragma("unroll")                                                    \
        for (int k = 0; k < 8; ++k) {                                        \
            acc[k].x += w * buf[k].x; acc[k].y += w * buf[k].y;              \
            acc[k].z += w * buf[k].z; acc[k].w += w * buf[k].w;              \
        }                                                                    \
    }

    // rotated 2-deep pipeline; n is even and >= 2
    LOAD(e0, 0);
    LOAD(e1, 1);
    for (int i = 0; i < n - 2; i += 2) {
        COMPUTE(e0);
        LOAD(e0, i + 2);
        COMPUTE(e1);
        LOAD(e1, i + 3);
    }
    COMPUTE(e0);
    COMPUTE(e1);

#undef LOAD
#undef COMPUTE

    // ---- in-block tree merge of the 4 wave partials (outside hot loop) ----
    // round 1: waves 2,3 publish; waves 0,1 absorb
    if (wave >= 2) {
#pragma unroll
        for (int k = 0; k < 8; ++k) sh_merge[wave - 2][k * 64 + lane] = acc[k];
        if (lane == 0) { sh_ml[wave - 2][0] = m; sh_ml[wave - 2][1] = l; }
    }
    __syncthreads();
    if (wave < 2) {
        const float pm = sh_ml[wave][0], pl = sh_ml[wave][1];
        const float mnew = fmaxf(m, pm);
        const float sa = __expf(m - mnew), sb = __expf(pm - mnew);
#pragma unroll
        for (int k = 0; k < 8; ++k) {
            const float4 q = sh_merge[wave][k * 64 + lane];
            acc[k].x = acc[k].x * sa + q.x * sb;
            acc[k].y = acc[k].y * sa + q.y * sb;
            acc[k].z = acc[k].z * sa + q.z * sb;
            acc[k].w = acc[k].w * sa + q.w * sb;
        }
        l = l * sa + pl * sb;
        m = mnew;
    }
    __syncthreads();
    // round 2: wave 1 publishes; wave 0 absorbs and writes out
    if (wave == 1) {
#pragma unroll
        for (int k = 0; k < 8; ++k) sh_merge[0][k * 64 + lane] = acc[k];
        if (lane == 0) { sh_ml[0][0] = m; sh_ml[0][1] = l; }
    }
    __syncthreads();
    if (wave == 0) {
        const float pm = sh_ml[0][0], pl = sh_ml[0][1];
        const float mnew = fmaxf(m, pm);
        const float sa = __expf(m - mnew), sb = __expf(pm - mnew);
        float* aout = acc_ws + ((size_t)b * nchunk + c) * kD;
#pragma unroll
        for (int k = 0; k < 8; ++k) {
            const float4 q = sh_merge[0][k * 64 + lane];
            float4 r;
            r.x = acc[k].x * sa + q.x * sb;
            r.y = acc[k].y * sa + q.y * sb;
            r.z = acc[k].z * sa + q.z * sb;
            r.w = acc[k].w * sa + q.w * sb;
            *reinterpret_cast<float4*>(aout + 256 * k + 4 * lane) = r;
        }
        if (lane == 0) {
            float* ml = ml_ws + ((size_t)b * nchunk + c) * 2;
            ml[0] = mnew;
            ml[1] = l * sa + pl * sb;
        }
    }
}

// Pass 2: exact cross-partial softmax combine, parallel over D slices.
// grid = (kD/256, B), block = 64 (one wave owns 256 columns). np = nchunk.
__global__ __launch_bounds__(64)
void attn_combine(const float* __restrict__ acc_ws,
                  const float* __restrict__ ml_ws,
                  float* __restrict__ out,
                  int np)
{
    const int slice = blockIdx.x;           // 0..7
    const int b     = blockIdx.y;
    const int t     = threadIdx.x;          // 0..63
    const int col   = slice * 256 + 4 * t;

    const float* ml = ml_ws + (size_t)b * np * 2;
    float M = -INFINITY;
    for (int p = 0; p < np; ++p) M = fmaxf(M, ml[2 * p]);

    float L = 0.f;
    float4 o = {0.f, 0.f, 0.f, 0.f};
    for (int p = 0; p < np; ++p) {
        const float coef = __expf(ml[2 * p] - M);
        L += ml[2 * p + 1] * coef;
        const float4 a = *reinterpret_cast<const float4*>(
            acc_ws + ((size_t)b * np + p) * kD + col);
        o.x += coef * a.x; o.y += coef * a.y;
        o.z += coef * a.z; o.w += coef * a.w;
    }
    const float inv = 1.f / L;
    float4 r = {o.x * inv, o.y * inv, o.z * inv, o.w * inv};
    *reinterpret_cast<float4*>(out + (size_t)b * kD + col) = r;
}

} // namespace

extern "C" void kernel_launch(void* const* d_in, const int* in_sizes, int n_in,
                              void* d_out, int out_size, void* d_ws, size_t ws_size,
                              hipStream_t stream) {
    const float* h = (const float*)d_in[0];   // decoder_hidden [B, D]
    const float* E = (const float*)d_in[1];   // encoder_states [B, S, D]
    float* out = (float*)d_out;

    // nchunk=32 -> 1024 blocks = exactly 4 resident blocks/CU (VGPR<=128,
    // LDS 24KB), zero tail. Halve if the workspace is too small.
    int nchunk = 32;
    while (nchunk > 1 &&
           (size_t)kB * nchunk * (kD + 2) * sizeof(float) > ws_size)
        nchunk >>= 1;

    float* acc_ws = (float*)d_ws;                        // [B, nchunk, D]
    float* ml_ws  = acc_ws + (size_t)kB * nchunk * kD;   // [B, nchunk, 2]

    dim3 g1(nchunk, kB);
    attn_partial<<<g1, 256, 0, stream>>>(h, E, acc_ws, ml_ws, nchunk);
    dim3 g2(kD / 256, kB);
    attn_combine<<<g2, 64, 0, stream>>>(acc_ws, ml_ws, out, nchunk);
}

// Round 6
// 168.781 us; speedup vs baseline: 2.2202x; 2.2202x over previous
//
#include <hip/hip_runtime.h>
#include <math.h>

namespace {

constexpr int kB = 32;
constexpr int kS = 4096;
constexpr int kD = 2048;
constexpr int kNW = 4;   // waves per block

typedef float v4f __attribute__((ext_vector_type(4)));

// Pass 1: single-read flash partial, pair-processed + register double-buffered.
// grid = (nchunk, B), block = 256 (4 waves, independent until the epilogue).
// Wave w owns rows {w, w+4, ...}; a row lives entirely in the wave's registers
// (lane covers d = 256*k + 4*lane). Rows are processed in PAIRS so the two
// 6-step butterfly chains interleave and the online-softmax rescale runs once
// per pair. Two pair-buffers rotate so 16 row-loads are in flight during
// compute. E is streamed with NON-TEMPORAL loads (read exactly once, no reuse
// -> don't allocate in L2/L3). Epilogue: LDS tree-merge of the 4 wave partials
// so each block writes ONE partial (8.4 MB instead of 33.6 MB).
// VGPR budget: hreg 32 + 4x pair-buf 128 + acc 32 + temps ~ 220 -> fits the
// 256 cap of __launch_bounds__(256,2) with NO spill (R5's (256,4)=128 spilled).
__global__ __launch_bounds__(256, 2)
void attn_partial(const float* __restrict__ h,      // [B, D]
                  const float* __restrict__ E,      // [B, S, D]
                  float* __restrict__ acc_ws,       // [B, nchunk, D]
                  float* __restrict__ ml_ws,        // [B, nchunk, 2]
                  int nchunk)
{
    const int c    = blockIdx.x;
    const int b    = blockIdx.y;
    const int t    = threadIdx.x;
    const int lane = t & 63;
    const int wave = t >> 6;
    const int cs   = kS / nchunk;     // rows per chunk
    const int s0   = c * cs;
    const int P    = cs / kNW / 2;    // pairs per wave (even, >= 2)

    __shared__ v4f   sh_merge[2][512];   // 16 KB, epilogue only
    __shared__ float sh_ml[2][2];

    const float* hb = h + (size_t)b * kD;
    v4f hreg[8];
#pragma unroll
    for (int k = 0; k < 8; ++k)
        hreg[k] = *reinterpret_cast<const v4f*>(hb + 256 * k + 4 * lane);

    v4f acc[8];
#pragma unroll
    for (int k = 0; k < 8; ++k) acc[k] = (v4f)(0.f);
    float m = -INFINITY, l = 0.f;

    // pair j covers per-wave rows 2j and 2j+1 -> global stride kNW*kD each
    const float* Eb = E + ((size_t)b * kS + s0 + wave) * kD + 4 * lane;

    v4f e0a[8], e0b[8], e1a[8], e1b[8];

#define LOADP(ra, rb, j)                                                     \
    {                                                                        \
        const float* _r0 = Eb + (size_t)(2 * (j)) * (kNW * kD);              \
        const float* _r1 = _r0 + (kNW * kD);                                 \
        _Pragma("unroll")                                                    \
        for (int k = 0; k < 8; ++k) {                                        \
            ra[k] = __builtin_nontemporal_load(                              \
                reinterpret_cast<const v4f*>(_r0 + 256 * k));                \
            rb[k] = __builtin_nontemporal_load(                              \
                reinterpret_cast<const v4f*>(_r1 + 256 * k));                \
        }                                                                    \
    }

#define COMPP(ra, rb)                                                        \
    {                                                                        \
        v4f va = (v4f)(0.f), vb = (v4f)(0.f);                                \
        _Pragma("unroll")                                                    \
        for (int k = 0; k < 8; ++k) {                                        \
            va += ra[k] * hreg[k];                                           \
            vb += rb[k] * hreg[k];                                           \
        }                                                                    \
        float pa = va.x + va.y + va.z + va.w;                                \
        float pb = vb.x + vb.y + vb.z + vb.w;                                \
        _Pragma("unroll")                                                    \
        for (int off = 32; off > 0; off >>= 1) {                             \
            pa += __shfl_xor(pa, off, 64);                                   \
            pb += __shfl_xor(pb, off, 64);                                   \
        }                                                                    \
        const float mnew = fmaxf(m, fmaxf(pa, pb));  /* v_max3 */            \
        if (mnew > m) {              /* wave-uniform; rare */                \
            const float scale = __expf(m - mnew);                            \
            _Pragma("unroll")                                                \
            for (int k = 0; k < 8; ++k) acc[k] *= scale;                     \
            l *= scale;                                                      \
            m = mnew;                                                        \
        }                                                                    \
        const float wa = __expf(pa - m);                                     \
        const float wb = __expf(pb - m);                                     \
        l += wa + wb;                                                        \
        _Pragma("unroll")                                                    \
        for (int k = 0; k < 8; ++k)                                          \
            acc[k] += wa * ra[k] + wb * rb[k];                               \
    }

    // rotated 2-deep pair pipeline; P is even and >= 2
    LOADP(e0a, e0b, 0);
    LOADP(e1a, e1b, 1);
    for (int j = 0; j < P - 2; j += 2) {
        COMPP(e0a, e0b);
        LOADP(e0a, e0b, j + 2);
        COMPP(e1a, e1b);
        LOADP(e1a, e1b, j + 3);
    }
    COMPP(e0a, e0b);
    COMPP(e1a, e1b);

#undef LOADP
#undef COMPP

    // ---- epilogue: LDS tree-merge of the 4 wave partials ----
    // round 1: waves 2,3 publish; waves 0,1 absorb
    if (wave >= 2) {
#pragma unroll
        for (int k = 0; k < 8; ++k) sh_merge[wave - 2][k * 64 + lane] = acc[k];
        if (lane == 0) { sh_ml[wave - 2][0] = m; sh_ml[wave - 2][1] = l; }
    }
    __syncthreads();
    if (wave < 2) {
        const float pm = sh_ml[wave][0], pl = sh_ml[wave][1];
        const float mnew = fmaxf(m, pm);
        const float sa = __expf(m - mnew), sb = __expf(pm - mnew);
#pragma unroll
        for (int k = 0; k < 8; ++k)
            acc[k] = acc[k] * sa + sh_merge[wave][k * 64 + lane] * sb;
        l = l * sa + pl * sb;
        m = mnew;
    }
    __syncthreads();
    // round 2: wave 1 publishes; wave 0 absorbs and writes the block partial
    if (wave == 1) {
#pragma unroll
        for (int k = 0; k < 8; ++k) sh_merge[0][k * 64 + lane] = acc[k];
        if (lane == 0) { sh_ml[0][0] = m; sh_ml[0][1] = l; }
    }
    __syncthreads();
    if (wave == 0) {
        const float pm = sh_ml[0][0], pl = sh_ml[0][1];
        const float mnew = fmaxf(m, pm);
        const float sa = __expf(m - mnew), sb = __expf(pm - mnew);
        float* aout = acc_ws + ((size_t)b * nchunk + c) * kD;
#pragma unroll
        for (int k = 0; k < 8; ++k) {
            v4f r = acc[k] * sa + sh_merge[0][k * 64 + lane] * sb;
            *reinterpret_cast<v4f*>(aout + 256 * k + 4 * lane) = r;
        }
        if (lane == 0) {
            float* ml = ml_ws + ((size_t)b * nchunk + c) * 2;
            ml[0] = mnew;
            ml[1] = l * sa + pl * sb;
        }
    }
}

// Pass 2: exact cross-partial softmax combine, parallel over D slices.
// grid = (kD/256, B), block = 64 (one wave owns 256 columns). np = nchunk.
__global__ __launch_bounds__(64)
void attn_combine(const float* __restrict__ acc_ws,
                  const float* __restrict__ ml_ws,
                  float* __restrict__ out,
                  int np)
{
    const int slice = blockIdx.x;           // 0..7
    const int b     = blockIdx.y;
    const int t     = threadIdx.x;          // 0..63
    const int col   = slice * 256 + 4 * t;

    const float* ml = ml_ws + (size_t)b * np * 2;
    float M = -INFINITY;
    for (int p = 0; p < np; ++p) M = fmaxf(M, ml[2 * p]);

    float L = 0.f;
    v4f o = (v4f)(0.f);
    for (int p = 0; p < np; ++p) {
        const float coef = __expf(ml[2 * p] - M);
        L += ml[2 * p + 1] * coef;
        const v4f a = *reinterpret_cast<const v4f*>(
            acc_ws + ((size_t)b * np + p) * kD + col);
        o += coef * a;
    }
    const float inv = 1.f / L;
    v4f r = o * inv;
    *reinterpret_cast<v4f*>(out + (size_t)b * kD + col) = r;
}

} // namespace

extern "C" void kernel_launch(void* const* d_in, const int* in_sizes, int n_in,
                              void* d_out, int out_size, void* d_ws, size_t ws_size,
                              hipStream_t stream) {
    const float* h = (const float*)d_in[0];   // decoder_hidden [B, D]
    const float* E = (const float*)d_in[1];   // encoder_states [B, S, D]
    float* out = (float*)d_out;

    // nchunk=16 -> 512 blocks = exactly 2 resident blocks/CU, no tail.
    int nchunk = 16;
    while (nchunk > 1 &&
           (size_t)kB * nchunk * (kD + 2) * sizeof(float) > ws_size)
        nchunk >>= 1;

    float* acc_ws = (float*)d_ws;                        // [B, nchunk, D]
    float* ml_ws  = acc_ws + (size_t)kB * nchunk * kD;   // [B, nchunk, 2]

    dim3 g1(nchunk, kB);
    attn_partial<<<g1, 256, 0, stream>>>(h, E, acc_ws, ml_ws, nchunk);
    dim3 g2(kD / 256, kB);
    attn_combine<<<g2, 64, 0, stream>>>(acc_ws, ml_ws, out, nchunk);
}